// Round 15
// baseline (161.450 us; speedup 1.0000x reference)
//
#include <hip/hip_runtime.h>

#define H_ 512
#define N_ 32
#define B_ 4
#define L_ 2048
#define LC 128
#define NC 16   // L_/LC

typedef _Float16 f16x8 __attribute__((ext_vector_type(8)));
typedef float f32x4 __attribute__((ext_vector_type(4)));
typedef float f32x2 __attribute__((ext_vector_type(2)));

__device__ inline unsigned short f2h(float f) {
  _Float16 h = (_Float16)f;   // RNE
  return __builtin_bit_cast(unsigned short, h);
}

// ---- packed fp32 complex-step helpers (VOP3P, op_sel half-selects) ----
__device__ inline f32x2 pk_mul_bl(f32x2 b, f32x2 uv) {
  f32x2 d;
  asm("v_pk_mul_f32 %0, %1, %2 op_sel:[0,0] op_sel_hi:[1,0]"
      : "=v"(d) : "v"(b), "v"(uv));
  return d;
}
__device__ inline f32x2 pk_mul_bh(f32x2 b, f32x2 uv) {
  f32x2 d;
  asm("v_pk_mul_f32 %0, %1, %2 op_sel:[0,1] op_sel_hi:[1,1]"
      : "=v"(d) : "v"(b), "v"(uv));
  return d;
}
// cross: d = {-a.hi*x.hi + c.lo, a.hi*x.lo + c.hi}
__device__ inline f32x2 pk_cross(f32x2 a, f32x2 x, f32x2 c) {
  f32x2 d;
  asm("v_pk_fma_f32 %0, %1, %2, %3 op_sel:[1,1,0] op_sel_hi:[1,0,1] neg_lo:[1,0,0]"
      : "=v"(d) : "v"(a), "v"(x), "v"(c));
  return d;
}
// real: d = {a.lo*x.lo + c.lo, a.lo*x.hi + c.hi}
__device__ inline f32x2 pk_real(f32x2 a, f32x2 x, f32x2 c) {
  f32x2 d;
  asm("v_pk_fma_f32 %0, %1, %2, %3 op_sel:[0,0,0] op_sel_hi:[0,1,1]"
      : "=v"(d) : "v"(a), "v"(x), "v"(c));
  return d;
}

// ---- DPP cross-lane (quad_perm): xor1 = 0xB1, xor2 = 0x4E ----
__device__ inline float dpp_xor1(float x) {
  int r = __builtin_amdgcn_update_dpp(0, __builtin_bit_cast(int, x), 0xB1, 0xF, 0xF, true);
  return __builtin_bit_cast(float, r);
}
__device__ inline float dpp_xor2(float x) {
  int r = __builtin_amdgcn_update_dpp(0, __builtin_bit_cast(int, x), 0x4E, 0xF, 0xF, true);
  return __builtin_bit_cast(float, r);
}

#define GLD_LDS16(gsrc, ldst)                                                        \
  __builtin_amdgcn_global_load_lds(                                                  \
      (const __attribute__((address_space(1))) unsigned int*)(gsrc),                 \
      (__attribute__((address_space(3))) unsigned int*)(ldst), 16, 0, 0)

// lane ln (0..15) owns n = ln*2, ln*2+1 of row h.
#define DISCRETIZE2(h, ln)                                                           \
  {                                                                                  \
    float dtv = expf(log_dt[(h)]);                                                   \
    _Pragma("unroll")                                                                \
    for (int i = 0; i < 2; ++i) {                                                    \
      int n = (ln) * 2 + i;                                                          \
      int idx = ((h) << 5) + n;                                                      \
      float ar = -expf(log_A_real[idx]);                                             \
      float ai = A_imag[idx];                                                        \
      float dr = 0.5f * dtv * ar, di = 0.5f * dtv * ai;                              \
      float omr = 1.0f - dr;                                                         \
      float inv = 1.0f / (omr * omr + di * di);                                      \
      Ad2[i] = (f32x2){(1.0f - dr * dr - di * di) * inv, 2.0f * di * inv};           \
      float br = B_ri[2 * n], bi = B_ri[2 * n + 1];                                  \
      Bd2[i] = (f32x2){dtv * (br * omr - bi * di) * inv,                             \
                       dtv * (br * di + bi * omr) * inv};                            \
      float2 c = ((const float2*)C_ri)[idx];                                         \
      Cc2[i] = (f32x2){c.x, c.y};                                                    \
    }                                                                                \
  }

// stage u tile into ut[16 h][132 t]: 4 scalar ds_writes per float4 (2-way conflict = free)
#define STAGE_UT16T()                                                                \
  {                                                                                  \
    int r = tid >> 2;                                                                \
    int q = tid & 3;                                                                 \
    _Pragma("unroll")                                                                \
    for (int i = 0; i < 2; ++i) {                                                    \
      int rr = r + 64 * i;                                                           \
      float4 vv = *(const float4*)(x + ((size_t)(b * L_ + c * LC + rr) * H_) +       \
                                   ht * 16 + q * 4);                                 \
      ut[q * 4 + 0][rr] = vv.x;                                                      \
      ut[q * 4 + 1][rr] = vv.y;                                                      \
      ut[q * 4 + 2][rr] = vv.z;                                                      \
      ut[q * 4 + 3][rr] = vv.w;                                                      \
    }                                                                                \
  }

// ================= fused scan (decoupled lookback, single kernel) =================
// grid (NC, 32, B_) x 256 thr = 2048 blocks = exactly 8 blocks/CU x 256 CU (all resident).
__global__ __launch_bounds__(256, 8) void scan_k(
    const float* __restrict__ x,
    const float* __restrict__ log_dt,
    const float* __restrict__ log_A_real,
    const float* __restrict__ A_imag,
    const float* __restrict__ B_ri,
    const float* __restrict__ C_ri,
    const float* __restrict__ Dv,
    const float* __restrict__ W1,
    const float* __restrict__ W2,
    unsigned short* __restrict__ WT1,
    unsigned short* __restrict__ WT2,
    float2* __restrict__ xend,
    int* __restrict__ flags,
    unsigned short* __restrict__ yN) {
  __shared__ float ut[16][132];   // 8448 B
  int c = blockIdx.x, ht = blockIdx.y, b = blockIdx.z;
  int tid = threadIdx.x;

  // ---- W transpose prologue (512 of 2048 blocks; before staging, uses ut as scratch) ----
  int flat = (b * 32 + ht) * NC + c;   // 0..2047
  if (flat < 512) {
    float(*tile)[33] = (float(*)[33]) & ut[0][0];   // 4224 B scratch
    const float* W = (flat >> 8) ? W2 : W1;
    unsigned short* WT = (flat >> 8) ? WT2 : WT1;
    int rem = flat & 255;
    int k0 = (rem & 15) << 5, j0 = (rem >> 4) << 5;
    int tx = tid & 31, ty = tid >> 5;
#pragma unroll
    for (int i = 0; i < 32; i += 8)
      tile[ty + i][tx] = W[(size_t)(k0 + ty + i) * H_ + j0 + tx];
    __syncthreads();
#pragma unroll
    for (int i = 0; i < 32; i += 8)
      WT[(size_t)(j0 + ty + i) * H_ + k0 + tx] = f2h(tile[tx][ty + i]);
    __syncthreads();
  }

  STAGE_UT16T()

  int grp = tid >> 4, ln = tid & 15;
  int h = ht * 16 + grp, bh = b * H_ + h;
  f32x2 Ad2[2], Bd2[2], Cc2[2];
  DISCRETIZE2(h, ln)
  float dd16 = Dv[h] * 0.0625f;   // D/16 folded per lane (butterfly sums x16)

  // CBd = C * Bd (complex)
  f32x2 CBd2[2];
#pragma unroll
  for (int i = 0; i < 2; ++i)
    CBd2[i] = (f32x2){Cc2[i].x * Bd2[i].x - Cc2[i].y * Bd2[i].y,
                      Cc2[i].x * Bd2[i].y + Cc2[i].y * Bd2[i].x};

  // Ad^128 by 7 squarings
  f32x2 Ap2[2];
#pragma unroll
  for (int i = 0; i < 2; ++i) {
    float pr = Ad2[i].x, pi = Ad2[i].y;
#pragma unroll
    for (int s = 0; s < 7; ++s) {
      float qr = pr * pr - pi * pi;
      float qi = 2.0f * pr * pi;
      pr = qr; pi = qi;
    }
    Ap2[i] = (f32x2){pr, pi};
  }
  __syncthreads();   // ut ready

  // ---- pass 1: zero-init local state scan (X += Ad*X + Bd*u), publish xend ----
  f32x2 X[2] = {(f32x2){0.f, 0.f}, (f32x2){0.f, 0.f}};
#pragma unroll 8
  for (int t = 0; t < LC; t += 2) {
    f32x2 pv = *(const f32x2*)&ut[grp][t];
#pragma unroll
    for (int i = 0; i < 2; ++i) {
      f32x2 t1 = pk_mul_bl(Bd2[i], pv);
      X[i] = pk_real(Ad2[i], X[i], pk_cross(Ad2[i], X[i], t1));
    }
#pragma unroll
    for (int i = 0; i < 2; ++i) {
      f32x2 t1 = pk_mul_bh(Bd2[i], pv);
      X[i] = pk_real(Ad2[i], X[i], pk_cross(Ad2[i], X[i], t1));
    }
  }
  if (c < NC - 1) {
    float2* dst = xend + ((size_t)bh * NC + c) * 32 + ln * 2;
    dst[0] = make_float2(X[0].x, X[0].y);
    dst[1] = make_float2(X[1].x, X[1].y);
  }
  __syncthreads();   // drains all waves' xend stores (vmcnt 0 before barrier)
  if (c < NC - 1 && tid == 0)
    __hip_atomic_store(&flags[(b * 32 + ht) * NC + c], 1,
                       __ATOMIC_RELEASE, __HIP_MEMORY_SCOPE_AGENT);

  // ---- poll predecessors (all 2048 blocks co-resident; bounded spin = fail-visible) ----
  if (c > 0) {
    const int base = (b * 32 + ht) * NC;
    int my = (tid < c) ? 0 : 1;
    for (int it = 0; it < (1 << 22); ++it) {
      if (tid < c && !my)
        my = __hip_atomic_load(&flags[base + tid], __ATOMIC_ACQUIRE,
                               __HIP_MEMORY_SCOPE_AGENT);
      if (__syncthreads_and(my)) break;
      __builtin_amdgcn_s_sleep(8);
    }
  }

  // ---- lookback: xstart = Horner over xend[c'<c] with Ad^128, 1-ahead prefetch ----
  X[0] = (f32x2){0.f, 0.f};
  X[1] = (f32x2){0.f, 0.f};
  if (c > 0) {
    const float4* e = (const float4*)(xend + (size_t)bh * NC * 32 + ln * 2);
    float4 Ecur = e[0];   // records are 32 float2 apart = 16 float4
    for (int cp = 0; cp < c; ++cp) {
      float4 Enext;
      if (cp + 1 < c) Enext = e[(cp + 1) * 16];
      f32x2 E0 = (f32x2){Ecur.x, Ecur.y};
      f32x2 E1 = (f32x2){Ecur.z, Ecur.w};
      X[0] = pk_real(Ap2[0], X[0], pk_cross(Ap2[0], X[0], E0));
      X[1] = pk_real(Ap2[1], X[1], pk_cross(Ap2[1], X[1], E1));
      Ecur = Enext;
    }
  }

  // Z0 = C * xstart
  f32x2 Z[2];
#pragma unroll
  for (int i = 0; i < 2; ++i) {
    f32x2 zero = (f32x2){0.f, 0.f};
    Z[i] = pk_real(Cc2[i], X[i], pk_cross(Cc2[i], X[i], zero));
  }

  // ---- pass 2: Z-space scan + 4-stage butterfly + scatter stores (reuses ut) ----
  unsigned short* yb = yN + ((size_t)b * L_ + c * LC + ln) * H_ + h;

#pragma unroll
  for (int w = 0; w < 8; ++w) {
    float v[16];
#define ZSTEP2(S)                                                            \
    {                                                                        \
      f32x2 pv = *(const f32x2*)&ut[grp][w * 16 + (S)];                      \
      _Pragma("unroll")                                                      \
      for (int i = 0; i < 2; ++i) {                                          \
        f32x2 t1 = pk_mul_bl(CBd2[i], pv);                                   \
        Z[i] = pk_real(Ad2[i], Z[i], pk_cross(Ad2[i], Z[i], t1));            \
      }                                                                      \
      v[(S)] = fmaf(dd16, pv.x, Z[0].x + Z[1].x);                            \
      _Pragma("unroll")                                                      \
      for (int i = 0; i < 2; ++i) {                                          \
        f32x2 t1 = pk_mul_bh(CBd2[i], pv);                                   \
        Z[i] = pk_real(Ad2[i], Z[i], pk_cross(Ad2[i], Z[i], t1));            \
      }                                                                      \
      v[(S) + 1] = fmaf(dd16, pv.y, Z[0].x + Z[1].x);                        \
    }
    ZSTEP2(0) ZSTEP2(2) ZSTEP2(4) ZSTEP2(6)
    ZSTEP2(8) ZSTEP2(10) ZSTEP2(12) ZSTEP2(14)
#define BFLY1(J)                                                             \
    {                                                                        \
      bool hi = (ln & 1) != 0;                                               \
      float snd = hi ? v[(J)] : v[(J) + 1];                                  \
      float rcv = dpp_xor1(snd);                                             \
      float kp = hi ? v[(J) + 1] : v[(J)];                                   \
      v[(J)] = kp + rcv;                                                     \
    }
#define BFLY2(J)                                                             \
    {                                                                        \
      bool hi = (ln & 2) != 0;                                               \
      float snd = hi ? v[(J)] : v[(J) + 2];                                  \
      float rcv = dpp_xor2(snd);                                             \
      float kp = hi ? v[(J) + 2] : v[(J)];                                   \
      v[(J)] = kp + rcv;                                                     \
    }
#define BFLY4(J)                                                             \
    {                                                                        \
      bool hi = (ln & 4) != 0;                                               \
      float snd = hi ? v[(J)] : v[(J) + 4];                                  \
      float rcv = __shfl_xor(snd, 4);                                        \
      float kp = hi ? v[(J) + 4] : v[(J)];                                   \
      v[(J)] = kp + rcv;                                                     \
    }
    BFLY1(0) BFLY1(2) BFLY1(4) BFLY1(6) BFLY1(8) BFLY1(10) BFLY1(12) BFLY1(14)
    BFLY2(0) BFLY2(4) BFLY2(8) BFLY2(12)
    BFLY4(0) BFLY4(8)
    {
      bool hi = (ln & 8) != 0;
      float snd = hi ? v[0] : v[8];
      float rcv = __shfl_xor(snd, 8);
      float kp = hi ? v[8] : v[0];
      v[0] = kp + rcv;
    }
    yb[(size_t)(w * 16) * H_] = f2h(v[0]);
  }
}

// ---------------- fused GLU GEMM (fp16 MFMA, single-buffer 32KB) ----------------
__global__ __launch_bounds__(256) void glu_gemm_k(const unsigned short* __restrict__ yN,
                                                  const unsigned short* __restrict__ WT1,
                                                  const unsigned short* __restrict__ WT2,
                                                  float* __restrict__ out) {
  __shared__ __align__(16) char lds[32768];   // A:16KB  B1:8KB  B2:8KB
  int tid = threadIdx.x;
  int m0 = blockIdx.x * 128;
  int n0 = blockIdx.y * 64;
  int wave = tid >> 6;
  int lane = tid & 63;
  int wm = wave >> 1;
  int wn = wave & 1;
  int srow = tid >> 3;          // 0..31
  int scb = (tid & 7) * 16;     // col-bytes within 128B row

  f32x4 acc1[4][2], acc2[4][2];
#pragma unroll
  for (int mf = 0; mf < 4; ++mf)
#pragma unroll
    for (int nf = 0; nf < 2; ++nf) {
      f32x4 z; z[0] = 0.f; z[1] = 0.f; z[2] = 0.f; z[3] = 0.f;
      acc1[mf][nf] = z; acc2[mf][nf] = z;
    }

  const char* ybase = (const char*)yN;
  const char* b1base = (const char*)WT1;
  const char* b2base = (const char*)WT2;
  char* As_ = lds;
  char* B1_ = lds + 16384;
  char* B2_ = lds + 24576;

  for (int k0 = 0; k0 < H_; k0 += 64) {
#pragma unroll
    for (int i = 0; i < 4; ++i) {
      int row = i * 32 + srow;
      int sc = scb ^ ((row & 7) << 4);
      GLD_LDS16(ybase + ((size_t)(m0 + row) * H_ + k0) * 2 + sc, As_ + wave * 1024 + i * 4096);
    }
#pragma unroll
    for (int i = 0; i < 2; ++i) {
      int row = i * 32 + srow;
      int sc = scb ^ ((row & 7) << 4);
      GLD_LDS16(b1base + ((size_t)(n0 + row) * H_ + k0) * 2 + sc, B1_ + wave * 1024 + i * 4096);
      GLD_LDS16(b2base + ((size_t)(n0 + row) * H_ + k0) * 2 + sc, B2_ + wave * 1024 + i * 4096);
    }
    __syncthreads();
#pragma unroll
    for (int ks = 0; ks < 2; ++ks) {
      f16x8 a[4], b1[2], b2[2];
      int kb = ks * 64 + (lane >> 4) * 16;
#pragma unroll
      for (int mf = 0; mf < 4; ++mf) {
        int row = wm * 64 + mf * 16 + (lane & 15);
        a[mf] = *(const f16x8*)(As_ + row * 128 + (kb ^ ((row & 7) << 4)));
      }
#pragma unroll
      for (int nf = 0; nf < 2; ++nf) {
        int row = wn * 32 + nf * 16 + (lane & 15);
        int off = row * 128 + (kb ^ ((row & 7) << 4));
        b1[nf] = *(const f16x8*)(B1_ + off);
        b2[nf] = *(const f16x8*)(B2_ + off);
      }
#pragma unroll
      for (int mf = 0; mf < 4; ++mf)
#pragma unroll
        for (int nf = 0; nf < 2; ++nf) {
          acc1[mf][nf] = __builtin_amdgcn_mfma_f32_16x16x32_f16(a[mf], b1[nf], acc1[mf][nf], 0, 0, 0);
          acc2[mf][nf] = __builtin_amdgcn_mfma_f32_16x16x32_f16(a[mf], b2[nf], acc2[mf][nf], 0, 0, 0);
        }
    }
    __syncthreads();
  }
  int nb = n0 + wn * 32 + (lane & 15);
  int rbase = (lane >> 4) * 4;
#pragma unroll
  for (int mf = 0; mf < 4; ++mf)
#pragma unroll
    for (int nf = 0; nf < 2; ++nf)
#pragma unroll
      for (int r = 0; r < 4; ++r) {
        int m = m0 + wm * 64 + mf * 16 + rbase + r;
        float g1 = acc1[mf][nf][r];
        float g2 = acc2[mf][nf][r];
        out[(size_t)m * H_ + nb + nf * 16] = g1 / (1.0f + __expf(-g2));
      }
}

extern "C" void kernel_launch(void* const* d_in, const int* in_sizes, int n_in,
                              void* d_out, int out_size, void* d_ws, size_t ws_size,
                              hipStream_t stream) {
  (void)in_sizes; (void)n_in; (void)out_size; (void)ws_size;
  const float* x          = (const float*)d_in[0];
  const float* log_dt     = (const float*)d_in[1];
  const float* log_A_real = (const float*)d_in[2];
  const float* A_imag     = (const float*)d_in[3];
  const float* B_ri       = (const float*)d_in[4];
  const float* C_ri       = (const float*)d_in[5];
  const float* Dv         = (const float*)d_in[6];
  const float* W1         = (const float*)d_in[7];
  const float* W2         = (const float*)d_in[8];
  float* out = (float*)d_out;
  char* ws = (char*)d_ws;

  unsigned short* yN    = (unsigned short*)(ws);                      // 8 MiB
  float2*         xend  = (float2*)(ws + (8u << 20));                 // 8 MiB
  unsigned short* WT1   = (unsigned short*)(ws + (16u << 20));        // 512 KiB
  unsigned short* WT2   = (unsigned short*)(ws + (16u << 20) + (512u << 10));
  int*            flags = (int*)(ws + (17u << 20));                   // 8 KiB

  hipMemsetAsync(flags, 0, B_ * 32 * NC * sizeof(int), stream);

  scan_k<<<dim3(NC, 32, B_), 256, 0, stream>>>(
      x, log_dt, log_A_real, A_imag, B_ri, C_ri, Dv, W1, W2, WT1, WT2,
      xend, flags, yN);

  dim3 ggrid((B_ * L_) / 128, H_ / 64);
  glu_gemm_k<<<ggrid, 256, 0, stream>>>(yN, WT1, WT2, out);
}

// Round 16
// 49.246 us; speedup vs baseline: 3.2785x; 3.2785x over previous
//
#include <hip/hip_runtime.h>

#define H_ 512
#define N_ 32
#define B_ 4
#define L_ 2048
#define LC 128
#define NC 16   // L_/LC

typedef _Float16 f16x8 __attribute__((ext_vector_type(8)));
typedef float f32x4 __attribute__((ext_vector_type(4)));

__device__ inline unsigned short f2h(float f) {
  _Float16 h = (_Float16)f;
  return __builtin_bit_cast(unsigned short, h);
}
__device__ inline float2 cmul(float2 a, float2 b) {
  return make_float2(fmaf(a.x, b.x, -(a.y * b.y)), fmaf(a.x, b.y, a.y * b.x));
}

#define GLD_LDS16(gsrc, ldst)                                                        \
  __builtin_amdgcn_global_load_lds(                                                  \
      (const __attribute__((address_space(1))) unsigned int*)(gsrc),                 \
      (__attribute__((address_space(3))) unsigned int*)(ldst), 16, 0, 0)

// ---------------- transpose x (B,L,H) -> xT (B,H,L) fp32 (proven r1) ----------------
__global__ void transpose_k(const float* __restrict__ in, float* __restrict__ out) {
  __shared__ float tile[32][33];
  int b = blockIdx.z;
  int t0 = blockIdx.x * 32;
  int h0 = blockIdx.y * 32;
  int tx = threadIdx.x, ty = threadIdx.y;
  const float* src = in + (size_t)b * L_ * H_;
#pragma unroll
  for (int i = 0; i < 32; i += 8)
    tile[ty + i][tx] = src[(size_t)(t0 + ty + i) * H_ + h0 + tx];
  __syncthreads();
  float* dst = out + (size_t)b * H_ * L_;
#pragma unroll
  for (int i = 0; i < 32; i += 8)
    dst[(size_t)(h0 + ty + i) * L_ + t0 + tx] = tile[tx][ty + i];
}

// ---------------- transpose W (K,N) fp32 -> WT (N,K) fp16 (proven) ----------------
__global__ void wtrans_k(const float* __restrict__ W1, const float* __restrict__ W2,
                         unsigned short* __restrict__ WT1, unsigned short* __restrict__ WT2) {
  __shared__ float tile[32][33];
  const float* W = blockIdx.z ? W2 : W1;
  unsigned short* WT = blockIdx.z ? WT2 : WT1;
  int k0 = blockIdx.x * 32, j0 = blockIdx.y * 32;
  int tx = threadIdx.x, ty = threadIdx.y;
#pragma unroll
  for (int i = 0; i < 32; i += 8)
    tile[ty + i][tx] = W[(size_t)(k0 + ty + i) * H_ + j0 + tx];
  __syncthreads();
#pragma unroll
  for (int i = 0; i < 32; i += 8)
    WT[(size_t)(j0 + ty + i) * H_ + k0 + tx] = f2h(tile[tx][ty + i]);
}

// ---------------- ytrans: yT (B,H,L) fp16 -> yN (B,L,H) fp16 ----------------
__global__ void ytrans_k(const unsigned short* __restrict__ in, unsigned short* __restrict__ out) {
  __shared__ unsigned short tile[32][34];
  int b = blockIdx.z;
  int t0 = blockIdx.x * 32;
  int h0 = blockIdx.y * 32;
  int tx = threadIdx.x, ty = threadIdx.y;
  const unsigned short* src = in + (size_t)b * H_ * L_;
#pragma unroll
  for (int i = 0; i < 32; i += 8)
    tile[ty + i][tx] = src[(size_t)(h0 + ty + i) * L_ + t0 + tx];
  __syncthreads();
  unsigned short* dst = out + (size_t)b * L_ * H_;
#pragma unroll
  for (int i = 0; i < 32; i += 8)
    dst[(size_t)(t0 + ty + i) * H_ + h0 + tx] = tile[tx][ty + i];
}

// ================= toeplitz scan: one block per h =================
// GEMM0: xend[nri][bc] = E[nri][j] @ U[j][bc]        (replaces scan1)
// Horner in-block over c -> Xs                        (replaces phase2)
// GEMM1+GEMM2: y[t][bc] = T[t][j]@U + M[t][nri]@Xs   (replaces scan2)
// LDS regions (bytes):
#define O_U   0       // U  [64 bc][136 j] fp16   17408
#define O_BIG 17408   // E[64][136]f16 | kpart[128][33]f32 | T[128][136]f16 | M[128][72]f16 | ylds[128][68]f32
#define O_XEND (O_BIG + 17408)  // xend_l [64 nri][68 bc] fp32  17408 (upper half of BIG)
#define O_XS  52224   // Xs [64 bc][72 nri] fp16   9216
#define O_KV  61440   // kvec [128] fp32           512
__global__ __launch_bounds__(256) void toeplitz_k(
    const float* __restrict__ xT,
    const float* __restrict__ log_dt,
    const float* __restrict__ log_A_real,
    const float* __restrict__ A_imag,
    const float* __restrict__ B_ri,
    const float* __restrict__ C_ri,
    const float* __restrict__ Dv,
    unsigned short* __restrict__ yT) {
  __shared__ __align__(16) char slds[61952];
  int h = blockIdx.x;
  int tid = threadIdx.x;
  int wave = tid >> 6, lane = tid & 63;
  int wm = wave >> 1, wn = wave & 1;

  // ---- per-thread chain params: n = tid&31, s = tid>>5 (tau segment) ----
  int n = tid & 31, s = tid >> 5;
  float dtv = expf(log_dt[h]);
  float2 Ad, Bd, Cc;
  {
    int idx = (h << 5) + n;
    float ar = -expf(log_A_real[idx]);
    float ai = A_imag[idx];
    float dr = 0.5f * dtv * ar, di = 0.5f * dtv * ai;
    float omr = 1.0f - dr;
    float inv = 1.0f / (omr * omr + di * di);
    Ad = make_float2((1.0f - dr * dr - di * di) * inv, 2.0f * di * inv);
    float br = B_ri[2 * n], bi = B_ri[2 * n + 1];
    Bd = make_float2(dtv * (br * omr - bi * di) * inv, dtv * (br * di + bi * omr) * inv);
    float2 c = ((const float2*)C_ri)[idx];
    Cc = make_float2(c.x, c.y);
  }
  float2 Ad16 = Ad;
#pragma unroll
  for (int q = 0; q < 4; ++q) Ad16 = cmul(Ad16, Ad16);   // Ad^16
  float2 AdS = make_float2(1.f, 0.f);                    // Ad^(16*s)
  for (int q = 0; q < s; ++q) AdS = cmul(AdS, Ad16);

  // ---- phase E: E[n][j] = Ad^(127-j) * Bd ; rows: n=Re, 32+n=Im ----
  {
    float2 cur = cmul(AdS, Bd);   // Ad^(16s) * Bd, power p = s*16
#pragma unroll
    for (int jj = 0; jj < 16; ++jj) {
      int p = s * 16 + jj;
      int col = 127 - p;
      *(unsigned short*)(slds + O_BIG + n * 272 + col * 2) = f2h(cur.x);
      *(unsigned short*)(slds + O_BIG + (32 + n) * 272 + col * 2) = f2h(cur.y);
      cur = cmul(cur, Ad);
    }
  }
  // ---- U load: U[bc][j] = xT[b][h][c*128+j] fp16 ----
  {
    int bc = tid >> 2, q = tid & 3;
    const float4* src4 = (const float4*)(xT + ((size_t)(bc >> 4) * H_ + h) * L_ + (bc & 15) * 128);
#pragma unroll
    for (int oct = 0; oct < 8; ++oct) {
      float4 f = src4[oct * 4 + q];
      int j0 = (oct * 4 + q) * 4;
      unsigned int w0 = (unsigned int)f2h(f.x) | ((unsigned int)f2h(f.y) << 16);
      unsigned int w1 = (unsigned int)f2h(f.z) | ((unsigned int)f2h(f.w) << 16);
      *(uint2*)(slds + O_U + bc * 272 + j0 * 2) = make_uint2(w0, w1);
    }
  }
  __syncthreads();

  // ---- GEMM0: E(64x128) @ U(64bc x128)^T -> xend_l[64 nri][64 bc] fp32 ----
  {
    f32x4 acc0[2][2];
#pragma unroll
    for (int mf = 0; mf < 2; ++mf)
#pragma unroll
      for (int nf = 0; nf < 2; ++nf) { f32x4 z; z[0]=z[1]=z[2]=z[3]=0.f; acc0[mf][nf]=z; }
#pragma unroll
    for (int ks = 0; ks < 4; ++ks) {
      int kb = ks * 64 + (lane >> 4) * 16;
      f16x8 a[2], bfr[2];
#pragma unroll
      for (int mf = 0; mf < 2; ++mf)
        a[mf] = *(const f16x8*)(slds + O_BIG + (wm * 32 + mf * 16 + (lane & 15)) * 272 + kb);
#pragma unroll
      for (int nf = 0; nf < 2; ++nf)
        bfr[nf] = *(const f16x8*)(slds + O_U + (wn * 32 + nf * 16 + (lane & 15)) * 272 + kb);
#pragma unroll
      for (int mf = 0; mf < 2; ++mf)
#pragma unroll
        for (int nf = 0; nf < 2; ++nf)
          acc0[mf][nf] = __builtin_amdgcn_mfma_f32_16x16x32_f16(a[mf], bfr[nf], acc0[mf][nf], 0, 0, 0);
    }
    __syncthreads();   // E dead; write xend_l (upper half of BIG)
#pragma unroll
    for (int mf = 0; mf < 2; ++mf)
#pragma unroll
      for (int nf = 0; nf < 2; ++nf)
#pragma unroll
        for (int r = 0; r < 4; ++r) {
          int row = wm * 32 + mf * 16 + (lane >> 4) * 4 + r;
          int col = wn * 32 + nf * 16 + (lane & 15);
          *(float*)(slds + O_XEND + (row * 68 + col) * 4) = acc0[mf][nf][r];
        }
  }
  __syncthreads();

  // ---- Horner lookback (128 threads: n x b) -> Xs[bc][2n..2n+1] fp16 ----
  if (tid < 128) {
    int nn = tid & 31, b = tid >> 5;
    float2 Ap = Ad;   // this thread's n == nn since tid<128 -> n=tid&31 matches ✓
#pragma unroll
    for (int q = 0; q < 7; ++q) Ap = cmul(Ap, Ap);   // Ad^128
    float2 X = make_float2(0.f, 0.f);
    for (int c = 0; c < NC; ++c) {
      int bc = b * 16 + c;
      unsigned int w = (unsigned int)f2h(X.x) | ((unsigned int)f2h(X.y) << 16);
      *(unsigned int*)(slds + O_XS + bc * 144 + nn * 4) = w;
      float er = *(const float*)(slds + O_XEND + (nn * 68 + bc) * 4);
      float ei = *(const float*)(slds + O_XEND + ((32 + nn) * 68 + bc) * 4);
      X = make_float2(fmaf(Ap.x, X.x, fmaf(-Ap.y, X.y, er)),
                      fmaf(Ap.x, X.y, fmaf(Ap.y, X.x, ei)));
    }
  }
  __syncthreads();

  // ---- k-build: kpart[tau][n] = Re(C*Bd*Ad^tau) ----
  {
    float2 cur = cmul(cmul(Cc, Bd), AdS);
#pragma unroll
    for (int jj = 0; jj < 16; ++jj) {
      int tau = s * 16 + jj;
      *(float*)(slds + O_BIG + (tau * 33 + n) * 4) = cur.x;
      cur = cmul(cur, Ad);
    }
  }
  __syncthreads();
  if (tid < 128) {
    float acc = 0.f;
#pragma unroll
    for (int q = 0; q < 32; ++q)
      acc += *(const float*)(slds + O_BIG + (tid * 33 + q) * 4);
    *(float*)(slds + O_KV + tid * 4) = acc;
  }
  __syncthreads();

  // ---- T-fill: T[t][j] = k[t-j] (j<=t), diag + D ----
  {
    float Dh = Dv[h];
    const float* kv = (const float*)(slds + O_KV);
    int t = tid >> 1, j0 = (tid & 1) * 64;
#pragma unroll
    for (int g = 0; g < 16; ++g) {
      int j = j0 + g * 4;
      unsigned int w0, w1;
      unsigned short e[4];
#pragma unroll
      for (int ee = 0; ee < 4; ++ee) {
        int jj = j + ee;
        float v = 0.f;
        if (jj <= t) v = (jj == t) ? (kv[0] + Dh) : kv[t - jj];
        e[ee] = f2h(v);
      }
      w0 = (unsigned int)e[0] | ((unsigned int)e[1] << 16);
      w1 = (unsigned int)e[2] | ((unsigned int)e[3] << 16);
      *(uint2*)(slds + O_BIG + t * 272 + j * 2) = make_uint2(w0, w1);
    }
  }
  __syncthreads();

  // ---- GEMM1: y = T(128x128) @ U ----
  f32x4 accy[4][2];
#pragma unroll
  for (int mf = 0; mf < 4; ++mf)
#pragma unroll
    for (int nf = 0; nf < 2; ++nf) { f32x4 z; z[0]=z[1]=z[2]=z[3]=0.f; accy[mf][nf]=z; }
#pragma unroll
  for (int ks = 0; ks < 4; ++ks) {
    int kb = ks * 64 + (lane >> 4) * 16;
    f16x8 a[4], bfr[2];
#pragma unroll
    for (int mf = 0; mf < 4; ++mf)
      a[mf] = *(const f16x8*)(slds + O_BIG + (wm * 64 + mf * 16 + (lane & 15)) * 272 + kb);
#pragma unroll
    for (int nf = 0; nf < 2; ++nf)
      bfr[nf] = *(const f16x8*)(slds + O_U + (wn * 32 + nf * 16 + (lane & 15)) * 272 + kb);
#pragma unroll
    for (int mf = 0; mf < 4; ++mf)
#pragma unroll
      for (int nf = 0; nf < 2; ++nf)
        accy[mf][nf] = __builtin_amdgcn_mfma_f32_16x16x32_f16(a[mf], bfr[nf], accy[mf][nf], 0, 0, 0);
  }
  __syncthreads();   // T, U dead

  // ---- M-build: M[t][2n]=Re(C*Ad^(t+1)), M[t][2n+1]=-Im(...) ----
  {
    float2 cur = cmul(cmul(Cc, Ad), AdS);   // C * Ad^(s*16+1)
#pragma unroll
    for (int jj = 0; jj < 16; ++jj) {
      int t = s * 16 + jj;
      unsigned int w = (unsigned int)f2h(cur.x) | ((unsigned int)f2h(-cur.y) << 16);
      *(unsigned int*)(slds + O_BIG + t * 144 + n * 4) = w;
      cur = cmul(cur, Ad);
    }
  }
  __syncthreads();

  // ---- GEMM2: y += M(128x64) @ Xs(64bc x64)^T ----
#pragma unroll
  for (int ks = 0; ks < 2; ++ks) {
    int kb = ks * 64 + (lane >> 4) * 16;
    f16x8 a[4], bfr[2];
#pragma unroll
    for (int mf = 0; mf < 4; ++mf)
      a[mf] = *(const f16x8*)(slds + O_BIG + (wm * 64 + mf * 16 + (lane & 15)) * 144 + kb);
#pragma unroll
    for (int nf = 0; nf < 2; ++nf)
      bfr[nf] = *(const f16x8*)(slds + O_XS + (wn * 32 + nf * 16 + (lane & 15)) * 144 + kb);
#pragma unroll
    for (int mf = 0; mf < 4; ++mf)
#pragma unroll
      for (int nf = 0; nf < 2; ++nf)
        accy[mf][nf] = __builtin_amdgcn_mfma_f32_16x16x32_f16(a[mf], bfr[nf], accy[mf][nf], 0, 0, 0);
  }
  __syncthreads();   // M, Xs dead

  // ---- epilogue: ylds[t][bc] fp32 -> yT[b][h][c*128+t] fp16 ----
#pragma unroll
  for (int mf = 0; mf < 4; ++mf)
#pragma unroll
    for (int nf = 0; nf < 2; ++nf)
#pragma unroll
      for (int r = 0; r < 4; ++r) {
        int t = wm * 64 + mf * 16 + (lane >> 4) * 4 + r;
        int bc = wn * 32 + nf * 16 + (lane & 15);
        *(float*)(slds + O_BIG + (t * 68 + bc) * 4) = accy[mf][nf][r];
      }
  __syncthreads();
  {
    int bc = tid >> 2, tl = tid & 3;
    unsigned short* dst = yT + ((size_t)(bc >> 4) * H_ + h) * L_ + (bc & 15) * 128;
#pragma unroll
    for (int tt = 0; tt < 16; ++tt) {
      int t = tl * 32 + tt * 2;
      float v0 = *(const float*)(slds + O_BIG + (t * 68 + bc) * 4);
      float v1 = *(const float*)(slds + O_BIG + ((t + 1) * 68 + bc) * 4);
      unsigned int w = (unsigned int)f2h(v0) | ((unsigned int)f2h(v1) << 16);
      *(unsigned int*)(dst + t) = w;
    }
  }
}

// ---------------- fused GLU GEMM (fp16 MFMA, single-buffer 32KB) — unchanged ----------------
__global__ __launch_bounds__(256) void glu_gemm_k(const unsigned short* __restrict__ yN,
                                                  const unsigned short* __restrict__ WT1,
                                                  const unsigned short* __restrict__ WT2,
                                                  float* __restrict__ out) {
  __shared__ __align__(16) char lds[32768];
  int tid = threadIdx.x;
  int m0 = blockIdx.x * 128;
  int n0 = blockIdx.y * 64;
  int wave = tid >> 6, lane = tid & 63;
  int wm = wave >> 1, wn = wave & 1;
  int srow = tid >> 3;
  int scb = (tid & 7) * 16;

  f32x4 acc1[4][2], acc2[4][2];
#pragma unroll
  for (int mf = 0; mf < 4; ++mf)
#pragma unroll
    for (int nf = 0; nf < 2; ++nf) {
      f32x4 z; z[0]=z[1]=z[2]=z[3]=0.f;
      acc1[mf][nf] = z; acc2[mf][nf] = z;
    }

  const char* ybase = (const char*)yN;
  const char* b1base = (const char*)WT1;
  const char* b2base = (const char*)WT2;
  char* As_ = lds;
  char* B1_ = lds + 16384;
  char* B2_ = lds + 24576;

  for (int k0 = 0; k0 < H_; k0 += 64) {
#pragma unroll
    for (int i = 0; i < 4; ++i) {
      int row = i * 32 + srow;
      int sc = scb ^ ((row & 7) << 4);
      GLD_LDS16(ybase + ((size_t)(m0 + row) * H_ + k0) * 2 + sc, As_ + wave * 1024 + i * 4096);
    }
#pragma unroll
    for (int i = 0; i < 2; ++i) {
      int row = i * 32 + srow;
      int sc = scb ^ ((row & 7) << 4);
      GLD_LDS16(b1base + ((size_t)(n0 + row) * H_ + k0) * 2 + sc, B1_ + wave * 1024 + i * 4096);
      GLD_LDS16(b2base + ((size_t)(n0 + row) * H_ + k0) * 2 + sc, B2_ + wave * 1024 + i * 4096);
    }
    __syncthreads();
#pragma unroll
    for (int ks = 0; ks < 2; ++ks) {
      f16x8 a[4], b1[2], b2[2];
      int kb = ks * 64 + (lane >> 4) * 16;
#pragma unroll
      for (int mf = 0; mf < 4; ++mf) {
        int row = wm * 64 + mf * 16 + (lane & 15);
        a[mf] = *(const f16x8*)(As_ + row * 128 + (kb ^ ((row & 7) << 4)));
      }
#pragma unroll
      for (int nf = 0; nf < 2; ++nf) {
        int row = wn * 32 + nf * 16 + (lane & 15);
        int off = row * 128 + (kb ^ ((row & 7) << 4));
        b1[nf] = *(const f16x8*)(B1_ + off);
        b2[nf] = *(const f16x8*)(B2_ + off);
      }
#pragma unroll
      for (int mf = 0; mf < 4; ++mf)
#pragma unroll
        for (int nf = 0; nf < 2; ++nf) {
          acc1[mf][nf] = __builtin_amdgcn_mfma_f32_16x16x32_f16(a[mf], b1[nf], acc1[mf][nf], 0, 0, 0);
          acc2[mf][nf] = __builtin_amdgcn_mfma_f32_16x16x32_f16(a[mf], b2[nf], acc2[mf][nf], 0, 0, 0);
        }
    }
    __syncthreads();
  }
  int nb = n0 + wn * 32 + (lane & 15);
  int rbase = (lane >> 4) * 4;
#pragma unroll
  for (int mf = 0; mf < 4; ++mf)
#pragma unroll
    for (int nf = 0; nf < 2; ++nf)
#pragma unroll
      for (int r = 0; r < 4; ++r) {
        int m = m0 + wm * 64 + mf * 16 + rbase + r;
        float g1 = acc1[mf][nf][r];
        float g2 = acc2[mf][nf][r];
        out[(size_t)m * H_ + nb + nf * 16] = g1 / (1.0f + __expf(-g2));
      }
}

extern "C" void kernel_launch(void* const* d_in, const int* in_sizes, int n_in,
                              void* d_out, int out_size, void* d_ws, size_t ws_size,
                              hipStream_t stream) {
  (void)in_sizes; (void)n_in; (void)out_size; (void)ws_size;
  const float* x          = (const float*)d_in[0];
  const float* log_dt     = (const float*)d_in[1];
  const float* log_A_real = (const float*)d_in[2];
  const float* A_imag     = (const float*)d_in[3];
  const float* B_ri       = (const float*)d_in[4];
  const float* C_ri       = (const float*)d_in[5];
  const float* Dv         = (const float*)d_in[6];
  const float* W1         = (const float*)d_in[7];
  const float* W2         = (const float*)d_in[8];
  float* out = (float*)d_out;
  char* ws = (char*)d_ws;

  unsigned short* yN  = (unsigned short*)(ws);                        // 8 MiB
  float*          xT  = (float*)(ws + (8u << 20));                    // 16 MiB
  unsigned short* yT  = (unsigned short*)(ws + (24u << 20));          // 8 MiB
  unsigned short* WT1 = (unsigned short*)(ws + (32u << 20));          // 512 KiB
  unsigned short* WT2 = (unsigned short*)(ws + (32u << 20) + (512u << 10));

  dim3 tblock(32, 8);
  transpose_k<<<dim3(L_ / 32, H_ / 32, B_), tblock, 0, stream>>>(x, xT);
  wtrans_k<<<dim3(16, 16, 2), tblock, 0, stream>>>(W1, W2, WT1, WT2);

  toeplitz_k<<<H_, 256, 0, stream>>>(xT, log_dt, log_A_real, A_imag, B_ri, C_ri, Dv, yT);

  ytrans_k<<<dim3(L_ / 32, H_ / 32, B_), tblock, 0, stream>>>(yT, yN);

  dim3 ggrid((B_ * L_) / 128, H_ / 64);
  glu_gemm_k<<<ggrid, 256, 0, stream>>>(yN, WT1, WT2, out);
}

// Round 17
// 46.758 us; speedup vs baseline: 3.4529x; 1.0532x over previous
//
#include <hip/hip_runtime.h>

#define H_ 512
#define N_ 32
#define B_ 4
#define L_ 2048
#define LC 128
#define NC 16   // L_/LC

typedef _Float16 f16x8 __attribute__((ext_vector_type(8)));
typedef float f32x4 __attribute__((ext_vector_type(4)));

__device__ inline unsigned short f2h(float f) {
  _Float16 h = (_Float16)f;
  return __builtin_bit_cast(unsigned short, h);
}
__device__ inline float2 cmul(float2 a, float2 b) {
  return make_float2(fmaf(a.x, b.x, -(a.y * b.y)), fmaf(a.x, b.y, a.y * b.x));
}

#define GLD_LDS16(gsrc, ldst)                                                        \
  __builtin_amdgcn_global_load_lds(                                                  \
      (const __attribute__((address_space(1))) unsigned int*)(gsrc),                 \
      (__attribute__((address_space(3))) unsigned int*)(ldst), 16, 0, 0)

// ---------------- transpose x (B,L,H) fp32 -> xT (B,H,L) fp16 ----------------
__global__ void transpose_k(const float* __restrict__ in, unsigned short* __restrict__ out) {
  __shared__ float tile[32][33];
  int b = blockIdx.z;
  int t0 = blockIdx.x * 32;
  int h0 = blockIdx.y * 32;
  int tx = threadIdx.x, ty = threadIdx.y;
  const float* src = in + (size_t)b * L_ * H_;
#pragma unroll
  for (int i = 0; i < 32; i += 8)
    tile[ty + i][tx] = src[(size_t)(t0 + ty + i) * H_ + h0 + tx];
  __syncthreads();
  unsigned short* dst = out + (size_t)b * H_ * L_;
#pragma unroll
  for (int i = 0; i < 32; i += 8)
    dst[(size_t)(h0 + ty + i) * L_ + t0 + tx] = f2h(tile[tx][ty + i]);
}

// ---------------- transpose W (K,N) fp32 -> WT (N,K) fp16 (proven) ----------------
__global__ void wtrans_k(const float* __restrict__ W1, const float* __restrict__ W2,
                         unsigned short* __restrict__ WT1, unsigned short* __restrict__ WT2) {
  __shared__ float tile[32][33];
  const float* W = blockIdx.z ? W2 : W1;
  unsigned short* WT = blockIdx.z ? WT2 : WT1;
  int k0 = blockIdx.x * 32, j0 = blockIdx.y * 32;
  int tx = threadIdx.x, ty = threadIdx.y;
#pragma unroll
  for (int i = 0; i < 32; i += 8)
    tile[ty + i][tx] = W[(size_t)(k0 + ty + i) * H_ + j0 + tx];
  __syncthreads();
#pragma unroll
  for (int i = 0; i < 32; i += 8)
    WT[(size_t)(j0 + ty + i) * H_ + k0 + tx] = f2h(tile[tx][ty + i]);
}

// ---------------- ytrans: yT (B,H,L) fp16 -> yN (B,L,H) fp16 ----------------
__global__ void ytrans_k(const unsigned short* __restrict__ in, unsigned short* __restrict__ out) {
  __shared__ unsigned short tile[32][34];
  int b = blockIdx.z;
  int t0 = blockIdx.x * 32;
  int h0 = blockIdx.y * 32;
  int tx = threadIdx.x, ty = threadIdx.y;
  const unsigned short* src = in + (size_t)b * H_ * L_;
#pragma unroll
  for (int i = 0; i < 32; i += 8)
    tile[ty + i][tx] = src[(size_t)(h0 + ty + i) * L_ + t0 + tx];
  __syncthreads();
  unsigned short* dst = out + (size_t)b * L_ * H_;
#pragma unroll
  for (int i = 0; i < 32; i += 8)
    dst[(size_t)(t0 + ty + i) * H_ + h0 + tx] = tile[tx][ty + i];
}

// ================= toeplitz scan: one block per h (proven r16, fp16 U-load) =================
#define O_U   0       // U  [64 bc][136 j] fp16   17408
#define O_BIG 17408   // E | kpart | T | M | ylds
#define O_XEND (O_BIG + 17408)  // xend_l [64 nri][68 bc] fp32
#define O_XS  52224   // Xs [64 bc][72 nri] fp16   9216
#define O_KV  61440   // kvec [128] fp32           512
__global__ __launch_bounds__(256) void toeplitz_k(
    const unsigned short* __restrict__ xT,
    const float* __restrict__ log_dt,
    const float* __restrict__ log_A_real,
    const float* __restrict__ A_imag,
    const float* __restrict__ B_ri,
    const float* __restrict__ C_ri,
    const float* __restrict__ Dv,
    unsigned short* __restrict__ yT) {
  __shared__ __align__(16) char slds[61952];
  int h = blockIdx.x;
  int tid = threadIdx.x;
  int wave = tid >> 6, lane = tid & 63;
  int wm = wave >> 1, wn = wave & 1;

  int n = tid & 31, s = tid >> 5;
  float dtv = expf(log_dt[h]);
  float2 Ad, Bd, Cc;
  {
    int idx = (h << 5) + n;
    float ar = -expf(log_A_real[idx]);
    float ai = A_imag[idx];
    float dr = 0.5f * dtv * ar, di = 0.5f * dtv * ai;
    float omr = 1.0f - dr;
    float inv = 1.0f / (omr * omr + di * di);
    Ad = make_float2((1.0f - dr * dr - di * di) * inv, 2.0f * di * inv);
    float br = B_ri[2 * n], bi = B_ri[2 * n + 1];
    Bd = make_float2(dtv * (br * omr - bi * di) * inv, dtv * (br * di + bi * omr) * inv);
    float2 c = ((const float2*)C_ri)[idx];
    Cc = make_float2(c.x, c.y);
  }
  float2 Ad16 = Ad;
#pragma unroll
  for (int q = 0; q < 4; ++q) Ad16 = cmul(Ad16, Ad16);   // Ad^16
  float2 AdS = make_float2(1.f, 0.f);                    // Ad^(16*s)
  for (int q = 0; q < s; ++q) AdS = cmul(AdS, Ad16);

  // ---- E: E[n][j] = Ad^(127-j) * Bd ----
  {
    float2 cur = cmul(AdS, Bd);
#pragma unroll
    for (int jj = 0; jj < 16; ++jj) {
      int col = 127 - (s * 16 + jj);
      *(unsigned short*)(slds + O_BIG + n * 272 + col * 2) = f2h(cur.x);
      *(unsigned short*)(slds + O_BIG + (32 + n) * 272 + col * 2) = f2h(cur.y);
      cur = cmul(cur, Ad);
    }
  }
  // ---- U load (fp16 source, pure 16B copies) ----
  {
    int bc = tid >> 2, q = tid & 3;
    const uint4* src = (const uint4*)(xT + ((size_t)(bc >> 4) * H_ + h) * L_ + (bc & 15) * 128);
#pragma unroll
    for (int i = 0; i < 4; ++i) {
      uint4 v = src[q * 4 + i];
      *(uint4*)(slds + O_U + bc * 272 + (q * 4 + i) * 16) = v;
    }
  }
  __syncthreads();

  // ---- GEMM0: E(64x128) @ U^T -> xend_l fp32 ----
  {
    f32x4 acc0[2][2];
#pragma unroll
    for (int mf = 0; mf < 2; ++mf)
#pragma unroll
      for (int nf = 0; nf < 2; ++nf) { f32x4 z; z[0]=z[1]=z[2]=z[3]=0.f; acc0[mf][nf]=z; }
#pragma unroll
    for (int ks = 0; ks < 4; ++ks) {
      int kb = ks * 64 + (lane >> 4) * 16;
      f16x8 a[2], bfr[2];
#pragma unroll
      for (int mf = 0; mf < 2; ++mf)
        a[mf] = *(const f16x8*)(slds + O_BIG + (wm * 32 + mf * 16 + (lane & 15)) * 272 + kb);
#pragma unroll
      for (int nf = 0; nf < 2; ++nf)
        bfr[nf] = *(const f16x8*)(slds + O_U + (wn * 32 + nf * 16 + (lane & 15)) * 272 + kb);
#pragma unroll
      for (int mf = 0; mf < 2; ++mf)
#pragma unroll
        for (int nf = 0; nf < 2; ++nf)
          acc0[mf][nf] = __builtin_amdgcn_mfma_f32_16x16x32_f16(a[mf], bfr[nf], acc0[mf][nf], 0, 0, 0);
    }
    __syncthreads();
#pragma unroll
    for (int mf = 0; mf < 2; ++mf)
#pragma unroll
      for (int nf = 0; nf < 2; ++nf)
#pragma unroll
        for (int r = 0; r < 4; ++r) {
          int row = wm * 32 + mf * 16 + (lane >> 4) * 4 + r;
          int col = wn * 32 + nf * 16 + (lane & 15);
          *(float*)(slds + O_XEND + (row * 68 + col) * 4) = acc0[mf][nf][r];
        }
  }
  __syncthreads();

  // ---- Horner lookback -> Xs fp16 ----
  if (tid < 128) {
    int nn = tid & 31, b = tid >> 5;
    float2 Ap = Ad;
#pragma unroll
    for (int q = 0; q < 7; ++q) Ap = cmul(Ap, Ap);   // Ad^128
    float2 X = make_float2(0.f, 0.f);
    for (int c = 0; c < NC; ++c) {
      int bc = b * 16 + c;
      unsigned int w = (unsigned int)f2h(X.x) | ((unsigned int)f2h(X.y) << 16);
      *(unsigned int*)(slds + O_XS + bc * 144 + nn * 4) = w;
      float er = *(const float*)(slds + O_XEND + (nn * 68 + bc) * 4);
      float ei = *(const float*)(slds + O_XEND + ((32 + nn) * 68 + bc) * 4);
      X = make_float2(fmaf(Ap.x, X.x, fmaf(-Ap.y, X.y, er)),
                      fmaf(Ap.x, X.y, fmaf(Ap.y, X.x, ei)));
    }
  }
  __syncthreads();

  // ---- k-build ----
  {
    float2 cur = cmul(cmul(Cc, Bd), AdS);
#pragma unroll
    for (int jj = 0; jj < 16; ++jj) {
      int tau = s * 16 + jj;
      *(float*)(slds + O_BIG + (tau * 33 + n) * 4) = cur.x;
      cur = cmul(cur, Ad);
    }
  }
  __syncthreads();
  if (tid < 128) {
    float acc = 0.f;
#pragma unroll
    for (int q = 0; q < 32; ++q)
      acc += *(const float*)(slds + O_BIG + (tid * 33 + q) * 4);
    *(float*)(slds + O_KV + tid * 4) = acc;
  }
  __syncthreads();

  // ---- T-fill ----
  {
    float Dh = Dv[h];
    const float* kv = (const float*)(slds + O_KV);
    int t = tid >> 1, j0 = (tid & 1) * 64;
#pragma unroll
    for (int g = 0; g < 16; ++g) {
      int j = j0 + g * 4;
      unsigned short e[4];
#pragma unroll
      for (int ee = 0; ee < 4; ++ee) {
        int jj = j + ee;
        float v = 0.f;
        if (jj <= t) v = (jj == t) ? (kv[0] + Dh) : kv[t - jj];
        e[ee] = f2h(v);
      }
      unsigned int w0 = (unsigned int)e[0] | ((unsigned int)e[1] << 16);
      unsigned int w1 = (unsigned int)e[2] | ((unsigned int)e[3] << 16);
      *(uint2*)(slds + O_BIG + t * 272 + j * 2) = make_uint2(w0, w1);
    }
  }
  __syncthreads();

  // ---- GEMM1: y = T @ U ----
  f32x4 accy[4][2];
#pragma unroll
  for (int mf = 0; mf < 4; ++mf)
#pragma unroll
    for (int nf = 0; nf < 2; ++nf) { f32x4 z; z[0]=z[1]=z[2]=z[3]=0.f; accy[mf][nf]=z; }
#pragma unroll
  for (int ks = 0; ks < 4; ++ks) {
    int kb = ks * 64 + (lane >> 4) * 16;
    f16x8 a[4], bfr[2];
#pragma unroll
    for (int mf = 0; mf < 4; ++mf)
      a[mf] = *(const f16x8*)(slds + O_BIG + (wm * 64 + mf * 16 + (lane & 15)) * 272 + kb);
#pragma unroll
    for (int nf = 0; nf < 2; ++nf)
      bfr[nf] = *(const f16x8*)(slds + O_U + (wn * 32 + nf * 16 + (lane & 15)) * 272 + kb);
#pragma unroll
    for (int mf = 0; mf < 4; ++mf)
#pragma unroll
      for (int nf = 0; nf < 2; ++nf)
        accy[mf][nf] = __builtin_amdgcn_mfma_f32_16x16x32_f16(a[mf], bfr[nf], accy[mf][nf], 0, 0, 0);
  }
  __syncthreads();

  // ---- M-build ----
  {
    float2 cur = cmul(cmul(Cc, Ad), AdS);
#pragma unroll
    for (int jj = 0; jj < 16; ++jj) {
      int t = s * 16 + jj;
      unsigned int w = (unsigned int)f2h(cur.x) | ((unsigned int)f2h(-cur.y) << 16);
      *(unsigned int*)(slds + O_BIG + t * 144 + n * 4) = w;
      cur = cmul(cur, Ad);
    }
  }
  __syncthreads();

  // ---- GEMM2: y += M @ Xs^T ----
#pragma unroll
  for (int ks = 0; ks < 2; ++ks) {
    int kb = ks * 64 + (lane >> 4) * 16;
    f16x8 a[4], bfr[2];
#pragma unroll
    for (int mf = 0; mf < 4; ++mf)
      a[mf] = *(const f16x8*)(slds + O_BIG + (wm * 64 + mf * 16 + (lane & 15)) * 144 + kb);
#pragma unroll
    for (int nf = 0; nf < 2; ++nf)
      bfr[nf] = *(const f16x8*)(slds + O_XS + (wn * 32 + nf * 16 + (lane & 15)) * 144 + kb);
#pragma unroll
    for (int mf = 0; mf < 4; ++mf)
#pragma unroll
      for (int nf = 0; nf < 2; ++nf)
        accy[mf][nf] = __builtin_amdgcn_mfma_f32_16x16x32_f16(a[mf], bfr[nf], accy[mf][nf], 0, 0, 0);
  }
  __syncthreads();

  // ---- epilogue ----
#pragma unroll
  for (int mf = 0; mf < 4; ++mf)
#pragma unroll
    for (int nf = 0; nf < 2; ++nf)
#pragma unroll
      for (int r = 0; r < 4; ++r) {
        int t = wm * 64 + mf * 16 + (lane >> 4) * 4 + r;
        int bc = wn * 32 + nf * 16 + (lane & 15);
        *(float*)(slds + O_BIG + (t * 68 + bc) * 4) = accy[mf][nf][r];
      }
  __syncthreads();
  {
    int bc = tid >> 2, tl = tid & 3;
    unsigned short* dst = yT + ((size_t)(bc >> 4) * H_ + h) * L_ + (bc & 15) * 128;
#pragma unroll
    for (int tt = 0; tt < 16; ++tt) {
      int t = tl * 32 + tt * 2;
      float v0 = *(const float*)(slds + O_BIG + (t * 68 + bc) * 4);
      float v1 = *(const float*)(slds + O_BIG + ((t + 1) * 68 + bc) * 4);
      unsigned int w = (unsigned int)f2h(v0) | ((unsigned int)f2h(v1) << 16);
      *(unsigned int*)(dst + t) = w;
    }
  }
}

// ---------------- fused GLU GEMM: BM=64, BN=64, 4 blocks/CU ----------------
__global__ __launch_bounds__(256) void glu_gemm_k(const unsigned short* __restrict__ yN,
                                                  const unsigned short* __restrict__ WT1,
                                                  const unsigned short* __restrict__ WT2,
                                                  float* __restrict__ out) {
  __shared__ __align__(16) char lds[24576];   // A:8KB  B1:8KB  B2:8KB
  int tid = threadIdx.x;
  int m0 = blockIdx.x * 64;
  int n0 = blockIdx.y * 64;
  int wave = tid >> 6, lane = tid & 63;
  int wm = wave >> 1, wn = wave & 1;
  int srow = tid >> 3;          // 0..31
  int scb = (tid & 7) * 16;

  f32x4 acc1[2][2], acc2[2][2];
#pragma unroll
  for (int mf = 0; mf < 2; ++mf)
#pragma unroll
    for (int nf = 0; nf < 2; ++nf) {
      f32x4 z; z[0]=z[1]=z[2]=z[3]=0.f;
      acc1[mf][nf] = z; acc2[mf][nf] = z;
    }

  const char* ybase = (const char*)yN;
  const char* b1base = (const char*)WT1;
  const char* b2base = (const char*)WT2;
  char* As_ = lds;
  char* B1_ = lds + 8192;
  char* B2_ = lds + 16384;

  for (int k0 = 0; k0 < H_; k0 += 64) {
#pragma unroll
    for (int i = 0; i < 2; ++i) {
      int row = i * 32 + srow;
      int sc = scb ^ ((row & 7) << 4);
      GLD_LDS16(ybase + ((size_t)(m0 + row) * H_ + k0) * 2 + sc, As_ + wave * 1024 + i * 4096);
      GLD_LDS16(b1base + ((size_t)(n0 + row) * H_ + k0) * 2 + sc, B1_ + wave * 1024 + i * 4096);
      GLD_LDS16(b2base + ((size_t)(n0 + row) * H_ + k0) * 2 + sc, B2_ + wave * 1024 + i * 4096);
    }
    __syncthreads();
#pragma unroll
    for (int ks = 0; ks < 2; ++ks) {
      f16x8 a[2], b1[2], b2[2];
      int kb = ks * 64 + (lane >> 4) * 16;
#pragma unroll
      for (int mf = 0; mf < 2; ++mf) {
        int row = wm * 32 + mf * 16 + (lane & 15);
        a[mf] = *(const f16x8*)(As_ + row * 128 + (kb ^ ((row & 7) << 4)));
      }
#pragma unroll
      for (int nf = 0; nf < 2; ++nf) {
        int row = wn * 32 + nf * 16 + (lane & 15);
        int off = row * 128 + (kb ^ ((row & 7) << 4));
        b1[nf] = *(const f16x8*)(B1_ + off);
        b2[nf] = *(const f16x8*)(B2_ + off);
      }
#pragma unroll
      for (int mf = 0; mf < 2; ++mf)
#pragma unroll
        for (int nf = 0; nf < 2; ++nf) {
          acc1[mf][nf] = __builtin_amdgcn_mfma_f32_16x16x32_f16(a[mf], b1[nf], acc1[mf][nf], 0, 0, 0);
          acc2[mf][nf] = __builtin_amdgcn_mfma_f32_16x16x32_f16(a[mf], b2[nf], acc2[mf][nf], 0, 0, 0);
        }
    }
    __syncthreads();
  }
  int nb = n0 + wn * 32 + (lane & 15);
  int rbase = (lane >> 4) * 4;
#pragma unroll
  for (int mf = 0; mf < 2; ++mf)
#pragma unroll
    for (int nf = 0; nf < 2; ++nf)
#pragma unroll
      for (int r = 0; r < 4; ++r) {
        int m = m0 + wm * 32 + mf * 16 + rbase + r;
        float g1 = acc1[mf][nf][r];
        float g2 = acc2[mf][nf][r];
        out[(size_t)m * H_ + nb + nf * 16] = g1 / (1.0f + __expf(-g2));
      }
}

extern "C" void kernel_launch(void* const* d_in, const int* in_sizes, int n_in,
                              void* d_out, int out_size, void* d_ws, size_t ws_size,
                              hipStream_t stream) {
  (void)in_sizes; (void)n_in; (void)out_size; (void)ws_size;
  const float* x          = (const float*)d_in[0];
  const float* log_dt     = (const float*)d_in[1];
  const float* log_A_real = (const float*)d_in[2];
  const float* A_imag     = (const float*)d_in[3];
  const float* B_ri       = (const float*)d_in[4];
  const float* C_ri       = (const float*)d_in[5];
  const float* Dv         = (const float*)d_in[6];
  const float* W1         = (const float*)d_in[7];
  const float* W2         = (const float*)d_in[8];
  float* out = (float*)d_out;
  char* ws = (char*)d_ws;

  unsigned short* yN   = (unsigned short*)(ws);                       // 8 MiB
  unsigned short* xT16 = (unsigned short*)(ws + (8u << 20));          // 8 MiB
  unsigned short* yT   = (unsigned short*)(ws + (16u << 20));         // 8 MiB
  unsigned short* WT1  = (unsigned short*)(ws + (24u << 20));         // 512 KiB
  unsigned short* WT2  = (unsigned short*)(ws + (24u << 20) + (512u << 10));

  dim3 tblock(32, 8);
  transpose_k<<<dim3(L_ / 32, H_ / 32, B_), tblock, 0, stream>>>(x, xT16);
  wtrans_k<<<dim3(16, 16, 2), tblock, 0, stream>>>(W1, W2, WT1, WT2);

  toeplitz_k<<<H_, 256, 0, stream>>>(xT16, log_dt, log_A_real, A_imag, B_ri, C_ri, Dv, yT);

  ytrans_k<<<dim3(L_ / 32, H_ / 32, B_), tblock, 0, stream>>>(yT, yN);

  dim3 ggrid((B_ * L_) / 64, H_ / 64);
  glu_gemm_k<<<ggrid, 256, 0, stream>>>(yN, WT1, WT2, out);
}

// Round 18
// 43.431 us; speedup vs baseline: 3.7174x; 1.0766x over previous
//
#include <hip/hip_runtime.h>

#define H_ 512
#define N_ 32
#define B_ 4
#define L_ 2048
#define LC 128
#define NC 16   // L_/LC

typedef _Float16 f16x8 __attribute__((ext_vector_type(8)));
typedef float f32x4 __attribute__((ext_vector_type(4)));

__device__ inline unsigned short f2h(float f) {
  _Float16 h = (_Float16)f;
  return __builtin_bit_cast(unsigned short, h);
}
__device__ inline float2 cmul(float2 a, float2 b) {
  return make_float2(fmaf(a.x, b.x, -(a.y * b.y)), fmaf(a.x, b.y, a.y * b.x));
}

#define GLD_LDS16(gsrc, ldst)                                                        \
  __builtin_amdgcn_global_load_lds(                                                  \
      (const __attribute__((address_space(1))) unsigned int*)(gsrc),                 \
      (__attribute__((address_space(3))) unsigned int*)(ldst), 16, 0, 0)

// ---------------- fused prep: z<4 -> x transpose (fp32->fp16), z>=4 -> W transpose ----------------
__global__ void prep_k(const float* __restrict__ in, unsigned short* __restrict__ out,
                       const float* __restrict__ W1, const float* __restrict__ W2,
                       unsigned short* __restrict__ WT1, unsigned short* __restrict__ WT2) {
  __shared__ float tile[32][33];
  int tx = threadIdx.x, ty = threadIdx.y;
  if (blockIdx.z >= 4) {
    if (blockIdx.x >= 16) return;
    const float* W = (blockIdx.z == 5) ? W2 : W1;
    unsigned short* WT = (blockIdx.z == 5) ? WT2 : WT1;
    int k0 = blockIdx.x * 32, j0 = blockIdx.y * 32;
#pragma unroll
    for (int i = 0; i < 32; i += 8)
      tile[ty + i][tx] = W[(size_t)(k0 + ty + i) * H_ + j0 + tx];
    __syncthreads();
#pragma unroll
    for (int i = 0; i < 32; i += 8)
      WT[(size_t)(j0 + ty + i) * H_ + k0 + tx] = f2h(tile[tx][ty + i]);
    return;
  }
  int b = blockIdx.z;
  int t0 = blockIdx.x * 32;
  int h0 = blockIdx.y * 32;
  const float* src = in + (size_t)b * L_ * H_;
#pragma unroll
  for (int i = 0; i < 32; i += 8)
    tile[ty + i][tx] = src[(size_t)(t0 + ty + i) * H_ + h0 + tx];
  __syncthreads();
  unsigned short* dst = out + (size_t)b * H_ * L_;
#pragma unroll
  for (int i = 0; i < 32; i += 8)
    dst[(size_t)(h0 + ty + i) * L_ + t0 + tx] = f2h(tile[tx][ty + i]);
}

// ---------------- ytrans: yT (B,H,L) fp16 -> yN (B,L,H) fp16 ----------------
__global__ void ytrans_k(const unsigned short* __restrict__ in, unsigned short* __restrict__ out) {
  __shared__ unsigned short tile[32][34];
  int b = blockIdx.z;
  int t0 = blockIdx.x * 32;
  int h0 = blockIdx.y * 32;
  int tx = threadIdx.x, ty = threadIdx.y;
  const unsigned short* src = in + (size_t)b * H_ * L_;
#pragma unroll
  for (int i = 0; i < 32; i += 8)
    tile[ty + i][tx] = src[(size_t)(h0 + ty + i) * L_ + t0 + tx];
  __syncthreads();
  unsigned short* dst = out + (size_t)b * L_ * H_;
#pragma unroll
  for (int i = 0; i < 32; i += 8)
    dst[(size_t)(t0 + ty + i) * H_ + h0 + tx] = tile[tx][ty + i];
}

// ================= toeplitz scan: one block per h, 512 threads (8 waves) =================
#define O_U   0       // U  [64 bc][136 j] fp16   17408
#define O_BIG 17408   // E | kpart | T | M | ylds   (34816 B)
#define O_XEND (O_BIG + 17408)  // xend_l [64 nri][68 bc] fp32 (upper half of BIG)
#define O_XS  52224   // Xs [64 bc][72 nri] fp16   9216
#define O_KV  61440   // kvec [128] fp32           512
__global__ __launch_bounds__(512) void toeplitz_k(
    const unsigned short* __restrict__ xT,
    const float* __restrict__ log_dt,
    const float* __restrict__ log_A_real,
    const float* __restrict__ A_imag,
    const float* __restrict__ B_ri,
    const float* __restrict__ C_ri,
    const float* __restrict__ Dv,
    unsigned short* __restrict__ yT) {
  __shared__ __align__(16) char slds[61952];
  int h = blockIdx.x;
  int tid = threadIdx.x;
  int wave = tid >> 6, lane = tid & 63;
  int wm = wave >> 2, wn = wave & 3;   // GEMM tiling: 2 m-waves x 4 n-waves

  // ---- per-thread chain params: n = tid&31, s8 = tid>>5 (8-step tau segment) ----
  int n = tid & 31, s8 = tid >> 5;     // s8 in 0..15
  float dtv = expf(log_dt[h]);
  float2 Ad, Bd, Cc;
  {
    int idx = (h << 5) + n;
    float ar = -expf(log_A_real[idx]);
    float ai = A_imag[idx];
    float dr = 0.5f * dtv * ar, di = 0.5f * dtv * ai;
    float omr = 1.0f - dr;
    float inv = 1.0f / (omr * omr + di * di);
    Ad = make_float2((1.0f - dr * dr - di * di) * inv, 2.0f * di * inv);
    float br = B_ri[2 * n], bi = B_ri[2 * n + 1];
    Bd = make_float2(dtv * (br * omr - bi * di) * inv, dtv * (br * di + bi * omr) * inv);
    float2 c = ((const float2*)C_ri)[idx];
    Cc = make_float2(c.x, c.y);
  }
  // AdS = Ad^(8*s8) by binary square-multiply
  float2 AdS;
  {
    float2 p = Ad;
    p = cmul(p, p); p = cmul(p, p); p = cmul(p, p);   // Ad^8
    float2 acc = make_float2(1.f, 0.f);
    if (s8 & 1) acc = cmul(acc, p);
    p = cmul(p, p);                                    // Ad^16
    if (s8 & 2) acc = cmul(acc, p);
    p = cmul(p, p);                                    // Ad^32
    if (s8 & 4) acc = cmul(acc, p);
    p = cmul(p, p);                                    // Ad^64
    if (s8 & 8) acc = cmul(acc, p);
    AdS = acc;
  }

  // ---- E: E[n][col=127-p] = Ad^p * Bd, p = s8*8+jj ----
  {
    float2 cur = cmul(AdS, Bd);
#pragma unroll
    for (int jj = 0; jj < 8; ++jj) {
      int col = 127 - (s8 * 8 + jj);
      *(unsigned short*)(slds + O_BIG + n * 272 + col * 2) = f2h(cur.x);
      *(unsigned short*)(slds + O_BIG + (32 + n) * 272 + col * 2) = f2h(cur.y);
      cur = cmul(cur, Ad);
    }
  }
  // ---- U load (fp16 source, 16B copies): bc = tid>>3, 2 uint4 per thread ----
  {
    int bc = tid >> 3, q = tid & 7;
    const uint4* src = (const uint4*)(xT + ((size_t)(bc >> 4) * H_ + h) * L_ + (bc & 15) * 128);
#pragma unroll
    for (int i = 0; i < 2; ++i) {
      uint4 v = src[q * 2 + i];
      *(uint4*)(slds + O_U + bc * 272 + (q * 2 + i) * 16) = v;
    }
  }
  __syncthreads();

  // ---- GEMM0: E(64x128) @ U^T -> xend_l fp32 ; wave tile 32x16 ----
  {
    f32x4 acc0[2];
#pragma unroll
    for (int mf = 0; mf < 2; ++mf) { f32x4 z; z[0]=z[1]=z[2]=z[3]=0.f; acc0[mf]=z; }
#pragma unroll
    for (int ks = 0; ks < 4; ++ks) {
      int kb = ks * 64 + (lane >> 4) * 16;
      f16x8 a[2], bfr;
#pragma unroll
      for (int mf = 0; mf < 2; ++mf)
        a[mf] = *(const f16x8*)(slds + O_BIG + (wm * 32 + mf * 16 + (lane & 15)) * 272 + kb);
      bfr = *(const f16x8*)(slds + O_U + (wn * 16 + (lane & 15)) * 272 + kb);
#pragma unroll
      for (int mf = 0; mf < 2; ++mf)
        acc0[mf] = __builtin_amdgcn_mfma_f32_16x16x32_f16(a[mf], bfr, acc0[mf], 0, 0, 0);
    }
    __syncthreads();   // E dead; write xend_l
#pragma unroll
    for (int mf = 0; mf < 2; ++mf)
#pragma unroll
      for (int r = 0; r < 4; ++r) {
        int row = wm * 32 + mf * 16 + (lane >> 4) * 4 + r;
        int col = wn * 16 + (lane & 15);
        *(float*)(slds + O_XEND + (row * 68 + col) * 4) = acc0[mf][r];
      }
  }
  __syncthreads();

  // ---- Horner lookback (128 threads) -> Xs fp16 ----
  if (tid < 128) {
    int nn = tid & 31, b = tid >> 5;
    float2 Ap = Ad;
#pragma unroll
    for (int q = 0; q < 7; ++q) Ap = cmul(Ap, Ap);   // Ad^128
    float2 X = make_float2(0.f, 0.f);
    for (int c = 0; c < NC; ++c) {
      int bc = b * 16 + c;
      unsigned int w = (unsigned int)f2h(X.x) | ((unsigned int)f2h(X.y) << 16);
      *(unsigned int*)(slds + O_XS + bc * 144 + nn * 4) = w;
      float er = *(const float*)(slds + O_XEND + (nn * 68 + bc) * 4);
      float ei = *(const float*)(slds + O_XEND + ((32 + nn) * 68 + bc) * 4);
      X = make_float2(fmaf(Ap.x, X.x, fmaf(-Ap.y, X.y, er)),
                      fmaf(Ap.x, X.y, fmaf(Ap.y, X.x, ei)));
    }
  }
  __syncthreads();

  // ---- k-build: kpart[tau][n] = Re(C*Bd*Ad^tau) ----
  {
    float2 cur = cmul(cmul(Cc, Bd), AdS);
#pragma unroll
    for (int jj = 0; jj < 8; ++jj) {
      int tau = s8 * 8 + jj;
      *(float*)(slds + O_BIG + (tau * 33 + n) * 4) = cur.x;
      cur = cmul(cur, Ad);
    }
  }
  __syncthreads();
  if (tid < 128) {
    float acc = 0.f;
#pragma unroll
    for (int q = 0; q < 32; ++q)
      acc += *(const float*)(slds + O_BIG + (tid * 33 + q) * 4);
    *(float*)(slds + O_KV + tid * 4) = acc;
  }
  __syncthreads();

  // ---- T-fill: T[t][j] = k[t-j] (j<=t), diag + D ; 512 thr: t=tid>>2, 32-col strip ----
  {
    float Dh = Dv[h];
    const float* kv = (const float*)(slds + O_KV);
    int t = tid >> 2, j0 = (tid & 3) * 32;
#pragma unroll
    for (int g = 0; g < 8; ++g) {
      int j = j0 + g * 4;
      unsigned short e[4];
#pragma unroll
      for (int ee = 0; ee < 4; ++ee) {
        int jj = j + ee;
        float v = 0.f;
        if (jj <= t) v = (jj == t) ? (kv[0] + Dh) : kv[t - jj];
        e[ee] = f2h(v);
      }
      unsigned int w0 = (unsigned int)e[0] | ((unsigned int)e[1] << 16);
      unsigned int w1 = (unsigned int)e[2] | ((unsigned int)e[3] << 16);
      *(uint2*)(slds + O_BIG + t * 272 + j * 2) = make_uint2(w0, w1);
    }
  }
  __syncthreads();

  // ---- GEMM1: y = T(128x128, lower-tri) @ U ; wave tile 64x16; wm=0 skips ks 2,3 ----
  f32x4 accy[4];
#pragma unroll
  for (int mf = 0; mf < 4; ++mf) { f32x4 z; z[0]=z[1]=z[2]=z[3]=0.f; accy[mf]=z; }
  {
    int ksmax = (wm == 0) ? 2 : 4;   // rows 0-63 have T[t][j]=0 for j>63
    for (int ks = 0; ks < ksmax; ++ks) {
      int kb = ks * 64 + (lane >> 4) * 16;
      f16x8 a[4], bfr;
#pragma unroll
      for (int mf = 0; mf < 4; ++mf)
        a[mf] = *(const f16x8*)(slds + O_BIG + (wm * 64 + mf * 16 + (lane & 15)) * 272 + kb);
      bfr = *(const f16x8*)(slds + O_U + (wn * 16 + (lane & 15)) * 272 + kb);
#pragma unroll
      for (int mf = 0; mf < 4; ++mf)
        accy[mf] = __builtin_amdgcn_mfma_f32_16x16x32_f16(a[mf], bfr, accy[mf], 0, 0, 0);
    }
  }
  __syncthreads();   // T, U dead

  // ---- M-build: M[t][2n]=Re(C*Ad^(t+1)), M[t][2n+1]=-Im ----
  {
    float2 cur = cmul(cmul(Cc, Ad), AdS);   // C * Ad^(8*s8+1)
#pragma unroll
    for (int jj = 0; jj < 8; ++jj) {
      int t = s8 * 8 + jj;
      unsigned int w = (unsigned int)f2h(cur.x) | ((unsigned int)f2h(-cur.y) << 16);
      *(unsigned int*)(slds + O_BIG + t * 144 + n * 4) = w;
      cur = cmul(cur, Ad);
    }
  }
  __syncthreads();

  // ---- GEMM2: y += M(128x64) @ Xs^T ----
#pragma unroll
  for (int ks = 0; ks < 2; ++ks) {
    int kb = ks * 64 + (lane >> 4) * 16;
    f16x8 a[4], bfr;
#pragma unroll
    for (int mf = 0; mf < 4; ++mf)
      a[mf] = *(const f16x8*)(slds + O_BIG + (wm * 64 + mf * 16 + (lane & 15)) * 144 + kb);
    bfr = *(const f16x8*)(slds + O_XS + (wn * 16 + (lane & 15)) * 144 + kb);
#pragma unroll
    for (int mf = 0; mf < 4; ++mf)
      accy[mf] = __builtin_amdgcn_mfma_f32_16x16x32_f16(a[mf], bfr, accy[mf], 0, 0, 0);
  }
  __syncthreads();   // M, Xs dead

  // ---- epilogue: ylds[t][bc] fp32 -> yT[b][h][c*128+t] fp16 ----
#pragma unroll
  for (int mf = 0; mf < 4; ++mf)
#pragma unroll
    for (int r = 0; r < 4; ++r) {
      int t = wm * 64 + mf * 16 + (lane >> 4) * 4 + r;
      int bc = wn * 16 + (lane & 15);
      *(float*)(slds + O_BIG + (t * 68 + bc) * 4) = accy[mf][r];
    }
  __syncthreads();
  {
    int bc = tid >> 3, tl = tid & 7;
    unsigned short* dst = yT + ((size_t)(bc >> 4) * H_ + h) * L_ + (bc & 15) * 128;
#pragma unroll
    for (int tt = 0; tt < 8; ++tt) {
      int t = tl * 16 + tt * 2;
      float v0 = *(const float*)(slds + O_BIG + (t * 68 + bc) * 4);
      float v1 = *(const float*)(slds + O_BIG + ((t + 1) * 68 + bc) * 4);
      unsigned int w = (unsigned int)f2h(v0) | ((unsigned int)f2h(v1) << 16);
      *(unsigned int*)(dst + t) = w;
    }
  }
}

// ---------------- fused GLU GEMM: BM=64, BN=64, 4 blocks/CU (proven r17) ----------------
__global__ __launch_bounds__(256) void glu_gemm_k(const unsigned short* __restrict__ yN,
                                                  const unsigned short* __restrict__ WT1,
                                                  const unsigned short* __restrict__ WT2,
                                                  float* __restrict__ out) {
  __shared__ __align__(16) char lds[24576];   // A:8KB  B1:8KB  B2:8KB
  int tid = threadIdx.x;
  int m0 = blockIdx.x * 64;
  int n0 = blockIdx.y * 64;
  int wave = tid >> 6, lane = tid & 63;
  int wm = wave >> 1, wn = wave & 1;
  int srow = tid >> 3;
  int scb = (tid & 7) * 16;

  f32x4 acc1[2][2], acc2[2][2];
#pragma unroll
  for (int mf = 0; mf < 2; ++mf)
#pragma unroll
    for (int nf = 0; nf < 2; ++nf) {
      f32x4 z; z[0]=z[1]=z[2]=z[3]=0.f;
      acc1[mf][nf] = z; acc2[mf][nf] = z;
    }

  const char* ybase = (const char*)yN;
  const char* b1base = (const char*)WT1;
  const char* b2base = (const char*)WT2;
  char* As_ = lds;
  char* B1_ = lds + 8192;
  char* B2_ = lds + 16384;

  for (int k0 = 0; k0 < H_; k0 += 64) {
#pragma unroll
    for (int i = 0; i < 2; ++i) {
      int row = i * 32 + srow;
      int sc = scb ^ ((row & 7) << 4);
      GLD_LDS16(ybase + ((size_t)(m0 + row) * H_ + k0) * 2 + sc, As_ + wave * 1024 + i * 4096);
      GLD_LDS16(b1base + ((size_t)(n0 + row) * H_ + k0) * 2 + sc, B1_ + wave * 1024 + i * 4096);
      GLD_LDS16(b2base + ((size_t)(n0 + row) * H_ + k0) * 2 + sc, B2_ + wave * 1024 + i * 4096);
    }
    __syncthreads();
#pragma unroll
    for (int ks = 0; ks < 2; ++ks) {
      f16x8 a[2], b1[2], b2[2];
      int kb = ks * 64 + (lane >> 4) * 16;
#pragma unroll
      for (int mf = 0; mf < 2; ++mf) {
        int row = wm * 32 + mf * 16 + (lane & 15);
        a[mf] = *(const f16x8*)(As_ + row * 128 + (kb ^ ((row & 7) << 4)));
      }
#pragma unroll
      for (int nf = 0; nf < 2; ++nf) {
        int row = wn * 32 + nf * 16 + (lane & 15);
        int off = row * 128 + (kb ^ ((row & 7) << 4));
        b1[nf] = *(const f16x8*)(B1_ + off);
        b2[nf] = *(const f16x8*)(B2_ + off);
      }
#pragma unroll
      for (int mf = 0; mf < 2; ++mf)
#pragma unroll
        for (int nf = 0; nf < 2; ++nf) {
          acc1[mf][nf] = __builtin_amdgcn_mfma_f32_16x16x32_f16(a[mf], b1[nf], acc1[mf][nf], 0, 0, 0);
          acc2[mf][nf] = __builtin_amdgcn_mfma_f32_16x16x32_f16(a[mf], b2[nf], acc2[mf][nf], 0, 0, 0);
        }
    }
    __syncthreads();
  }
  int nb = n0 + wn * 32 + (lane & 15);
  int rbase = (lane >> 4) * 4;
#pragma unroll
  for (int mf = 0; mf < 2; ++mf)
#pragma unroll
    for (int nf = 0; nf < 2; ++nf)
#pragma unroll
      for (int r = 0; r < 4; ++r) {
        int m = m0 + wm * 32 + mf * 16 + rbase + r;
        float g1 = acc1[mf][nf][r];
        float g2 = acc2[mf][nf][r];
        out[(size_t)m * H_ + nb + nf * 16] = g1 / (1.0f + __expf(-g2));
      }
}

extern "C" void kernel_launch(void* const* d_in, const int* in_sizes, int n_in,
                              void* d_out, int out_size, void* d_ws, size_t ws_size,
                              hipStream_t stream) {
  (void)in_sizes; (void)n_in; (void)out_size; (void)ws_size;
  const float* x          = (const float*)d_in[0];
  const float* log_dt     = (const float*)d_in[1];
  const float* log_A_real = (const float*)d_in[2];
  const float* A_imag     = (const float*)d_in[3];
  const float* B_ri       = (const float*)d_in[4];
  const float* C_ri       = (const float*)d_in[5];
  const float* Dv         = (const float*)d_in[6];
  const float* W1         = (const float*)d_in[7];
  const float* W2         = (const float*)d_in[8];
  float* out = (float*)d_out;
  char* ws = (char*)d_ws;

  unsigned short* yN   = (unsigned short*)(ws);                       // 8 MiB
  unsigned short* xT16 = (unsigned short*)(ws + (8u << 20));          // 8 MiB
  unsigned short* yT   = (unsigned short*)(ws + (16u << 20));         // 8 MiB
  unsigned short* WT1  = (unsigned short*)(ws + (24u << 20));         // 512 KiB
  unsigned short* WT2  = (unsigned short*)(ws + (24u << 20) + (512u << 10));

  dim3 tblock(32, 8);
  prep_k<<<dim3(L_ / 32, H_ / 32, 6), tblock, 0, stream>>>(x, xT16, W1, W2, WT1, WT2);

  toeplitz_k<<<H_, 512, 0, stream>>>(xT16, log_dt, log_A_real, A_imag, B_ri, C_ri, Dv, yT);

  ytrans_k<<<dim3(L_ / 32, H_ / 32, B_), tblock, 0, stream>>>(yT, yN);

  dim3 ggrid((B_ * L_) / 64, H_ / 64);
  glu_gemm_k<<<ggrid, 256, 0, stream>>>(yN, WT1, WT2, out);
}